// Round 15
// baseline (43.030 us; speedup 1.0000x reference)
//
#include <hip/hip_runtime.h>

#define NEG_SLOPE 0.2f

typedef __bf16 bf16x8 __attribute__((ext_vector_type(8)));
typedef float  f32x4  __attribute__((ext_vector_type(4)));
typedef float  f32x2  __attribute__((ext_vector_type(2)));

__device__ __forceinline__ float relu_f(float v) { return v > 0.f ? v : 0.f; }
__device__ __forceinline__ f32x2 pk_fma(f32x2 a, f32x2 b, f32x2 c) { return __builtin_elementwise_fma(a, b, c); }
__device__ __forceinline__ f32x2 pk_max(f32x2 a, f32x2 b) { return __builtin_elementwise_max(a, b); }
__device__ __forceinline__ f32x2 splat2(float s) { f32x2 r = {s, s}; return r; }
__device__ __forceinline__ f32x2 ld2(const float* p) { return *reinterpret_cast<const f32x2*>(p); }

// ---------------- prep: W1/W2 -> bf16 MFMA B-fragment order in d_ws ----------------
// (validated R7-R11) W1F[(n*64+l)*8+j] = bf16(W1[(l4*8+j)*128 + n*16+l15])
// W2F[((ks*2+nn)*64+l)*8+j] = bf16(W2[(j*16+ks*4+l4)*32 + nn*16+l15])  (row-permuted
// to match the z_store[row][l15*8+n] layout). Doing this ONCE here instead of per
// block removes ~2048 uncoalesced VMEM lines/wave from the fused kernel (R14 bug:
// in-block staging was ~27 us of TA occupancy per CU).
__global__ __launch_bounds__(256)
void prep_weights(const float* __restrict__ W1, const float* __restrict__ W2,
                  __bf16* __restrict__ W1F, __bf16* __restrict__ W2F)
{
    int idx = blockIdx.x * 256 + threadIdx.x;   // 0..8191
    int half = idx >> 12;                        // 0: W1, 1: W2
    int e    = idx & 4095;
    int j   = e & 7;
    int l   = (e >> 3) & 63;
    int t   = e >> 9;                            // 0..7
    int l15 = l & 15;
    int l4  = l >> 4;
    if (half == 0) {
        W1F[e] = (__bf16)W1[(l4 * 8 + j) * 128 + t * 16 + l15];
    } else {
        int ks = t >> 1, nn = t & 1;
        W2F[e] = (__bf16)W2[(j * 16 + ks * 4 + l4) * 32 + nn * 16 + l15];
    }
}

// ============ Fused kernel: GAT + MLP; fragments pre-swizzled in d_ws ============
// Block = 256 threads = 4 waves, 64 samples.
// Phase 0: compute g=1 reduced transform WRED (landmark feats linear in 6 pos
//          scalars -> x@Wl == p@WRED, exact algebra). Fragments load to VGPRs
//          (16 coalesced bf16x8 wave-loads, consumed in phase 2).
// Phase 1: GAT (validated R9/R14): wave w -> g=w&1, ch=(w>>1)&1; lane = sample.
// Phase 2: MLP via MFMA 16x16x32 bf16 (validated R8): B-frags from VGPRs.
// LDS: wred 2304 + lp 9216 + h 5120 + z 17408 = 34048 B -> 4 blocks/CU.
__global__ __launch_bounds__(256)
void scl_fused_kernel(
    const float* __restrict__ agent_pos, const float* __restrict__ agent_vel,
    const float* __restrict__ rel_lm, const float* __restrict__ other_pos,
    const float* __restrict__ lm_pos,
    const float* __restrict__ Wl, const float* __restrict__ bl,
    const float* __restrict__ Wr, const float* __restrict__ br,
    const float* __restrict__ We, const float* __restrict__ att,
    const float* __restrict__ bias,
    const bf16x8* __restrict__ W1F, const float* __restrict__ b1,
    const bf16x8* __restrict__ W2F, const float* __restrict__ b2,
    float* __restrict__ out, int Btot)
{
    __shared__ alignas(16) float  lds_wred[2][3][6][16];   // [side l/r][node j][pos k][ch]
    __shared__ alignas(16) float  lds_lp[2304];            // lp[2][2][64][9] f32
    __shared__ alignas(16) __bf16 lds_h[64][40];           // pooled GAT out
    __shared__ alignas(16) __bf16 lds_z[4][16][136];       // per-wave z (R8 layout)

    const int tid  = threadIdx.x;
    const int lane = tid & 63;
    const int w    = tid >> 6;
    const int g    = __builtin_amdgcn_readfirstlane(w & 1);
    const int ch   = __builtin_amdgcn_readfirstlane((w >> 1) & 1);
    const int wu   = __builtin_amdgcn_readfirstlane(w);
    const int CB   = ch * 8;

    int b = blockIdx.x * 64 + lane;
    if (b >= Btot) b = Btot - 1;            // clamp reads; barriers stay uniform

    const int o0[3] = {1, 0, 0};
    const int o1[3] = {2, 2, 1};

    // ---- fragment loads (coalesced 16B/lane; used only in phase 2) ----
    bf16x8 w1f[8], w2f[8];
#pragma unroll
    for (int n = 0; n < 8; ++n) w1f[n] = W1F[(n << 6) | lane];
#pragma unroll
    for (int t = 0; t < 8; ++t) w2f[t] = W2F[(t << 6) | lane];

    // ---------- phase 0: reduced g=1 transform matrices (exact algebra) ----
    if (tid < 192) {
#pragma unroll
        for (int q = 0; q < 3; ++q) {
            int e = tid * 3 + q;            // 0..575
            int c = e & 15;
            int r16 = e >> 4;               // (side*3+j)*6+k
            int k = r16 % 6, sj = r16 / 6, j = sj % 3, side = sj / 3;
            const float* Wm = side ? Wr : Wl;
            int m = k >> 1, isY = k & 1;
            float v = Wm[(4 + 2 * m + isY) * 16 + c];
            if (m == o0[j]) v += Wm[(10 + isY) * 16 + c];
            if (m == o1[j]) v += Wm[(12 + isY) * 16 + c];
            if (m == j)
                v += Wm[(0 + isY) * 16 + c] - Wm[(4 + isY) * 16 + c]
                   - Wm[(6 + isY) * 16 + c] - Wm[(8 + isY) * 16 + c]
                   - Wm[(10 + isY) * 16 + c] - Wm[(12 + isY) * 16 + c];
            lds_wred[side][j][k][c] = v;
        }
    }
    __syncthreads();    // B0: wred ready

    // ---------- phase 1: GAT ----------
    float px[3], py[3];
    f32x2 xl[3][4], xr[3][4];

    if (g == 0) {
        const float2* ap = reinterpret_cast<const float2*>(agent_pos + b * 6);
#pragma unroll
        for (int j = 0; j < 3; ++j) { px[j] = ap[j].x; py[j] = ap[j].y; }
        float xf[3][14];
#pragma unroll
        for (int j = 0; j < 3; ++j) {
            const float2 vel = reinterpret_cast<const float2*>(agent_vel + b * 6)[j];
            const float2* rl = reinterpret_cast<const float2*>(rel_lm + b * 18 + j * 6);
            const float4 op  = reinterpret_cast<const float4*>(other_pos + b * 12)[j];
            xf[j][0] = px[j]; xf[j][1] = py[j];
            xf[j][2] = vel.x; xf[j][3] = vel.y;
            xf[j][4] = rl[0].x; xf[j][5] = rl[0].y;
            xf[j][6] = rl[1].x; xf[j][7] = rl[1].y;
            xf[j][8] = rl[2].x; xf[j][9] = rl[2].y;
            xf[j][10] = op.x; xf[j][11] = op.y; xf[j][12] = op.z; xf[j][13] = op.w;
        }
#pragma unroll
        for (int cc = 0; cc < 4; ++cc) {
            f32x2 vbl = ld2(bl + CB + cc * 2), vbr = ld2(br + CB + cc * 2);
#pragma unroll
            for (int j = 0; j < 3; ++j) { xl[j][cc] = vbl; xr[j][cc] = vbr; }
        }
#pragma unroll
        for (int k = 0; k < 14; ++k) {
            f32x2 wl2[4], wr2[4];
#pragma unroll
            for (int cc = 0; cc < 4; ++cc) {
                wl2[cc] = ld2(Wl + k * 16 + CB + cc * 2);
                wr2[cc] = ld2(Wr + k * 16 + CB + cc * 2);
            }
#pragma unroll
            for (int j = 0; j < 3; ++j) {
                f32x2 xk = splat2(xf[j][k]);
#pragma unroll
                for (int cc = 0; cc < 4; ++cc) {
                    xl[j][cc] = pk_fma(xk, wl2[cc], xl[j][cc]);
                    xr[j][cc] = pk_fma(xk, wr2[cc], xr[j][cc]);
                }
            }
        }
    } else {
        const float2* lp2 = reinterpret_cast<const float2*>(lm_pos + b * 18);
#pragma unroll
        for (int m = 0; m < 3; ++m) { px[m] = lp2[m].x; py[m] = lp2[m].y; }
        float ps[6] = {px[0], py[0], px[1], py[1], px[2], py[2]};
#pragma unroll
        for (int cc = 0; cc < 4; ++cc) {
            f32x2 vbl = ld2(bl + CB + cc * 2), vbr = ld2(br + CB + cc * 2);
#pragma unroll
            for (int j = 0; j < 3; ++j) { xl[j][cc] = vbl; xr[j][cc] = vbr; }
        }
#pragma unroll
        for (int k = 0; k < 6; ++k) {
            f32x2 pk = splat2(ps[k]);
#pragma unroll
            for (int j = 0; j < 3; ++j) {
#pragma unroll
                for (int cc = 0; cc < 4; ++cc) {
                    xl[j][cc] = pk_fma(pk, ld2(&lds_wred[0][j][k][CB + cc * 2]), xl[j][cc]);
                    xr[j][cc] = pk_fma(pk, ld2(&lds_wred[1][j][k][CB + cc * 2]), xr[j][cc]);
                }
            }
        }
    }

    // ---- pairwise distances + edge geometry (e = j*3+i) ----
    float ax[9], ay[9], ad[9];
    {
        float dx, dy, d01, d02, d12;
        dx = px[0] - px[1]; dy = py[0] - py[1]; d01 = sqrtf(dx * dx + dy * dy);
        dx = px[0] - px[2]; dy = py[0] - py[2]; d02 = sqrtf(dx * dx + dy * dy);
        dx = px[1] - px[2]; dy = py[1] - py[2]; d12 = sqrtf(dx * dx + dy * dy);
#pragma unroll
        for (int i = 0; i < 3; ++i) {
#pragma unroll
            for (int j = 0; j < 3; ++j) {
                int e = j * 3 + i;
                if (i == j) {
                    const int a = o0[i], c2 = o1[i];
                    ax[e] = 0.5f * (px[a] + px[c2]) - px[i];
                    ay[e] = 0.5f * (py[a] + py[c2]) - py[i];
                    const float dA = (i == 0) ? d01 : ((i == 1) ? d01 : d02);
                    const float dB = (i == 0) ? d02 : ((i == 1) ? d12 : d12);
                    ad[e] = 0.5f * (dA + dB);
                } else {
                    ax[e] = px[j] - px[i];
                    ay[e] = py[j] - py[i];
                    ad[e] = ((i == 0 && j == 1) || (i == 1 && j == 0)) ? d01
                          : ((i == 0 && j == 2) || (i == 2 && j == 0)) ? d02 : d12;
                }
            }
        }
    }

    // ---- logit partials: cc-outer (R14, validated) ----
    f32x2 lpacc[9];
#pragma unroll
    for (int e = 0; e < 9; ++e) lpacc[e] = splat2(0.f);
#pragma unroll
    for (int cc = 0; cc < 4; ++cc) {
        f32x2 we0 = ld2(We + CB + cc * 2);
        f32x2 we1 = ld2(We + 16 + CB + cc * 2);
        f32x2 we2 = ld2(We + 32 + CB + cc * 2);
        f32x2 vat = ld2(att + CB + cc * 2);
#pragma unroll
        for (int j = 0; j < 3; ++j) {
#pragma unroll
            for (int i = 0; i < 3; ++i) {
                int e = j * 3 + i;
                f32x2 gg = xl[j][cc] + xr[i][cc];
                gg = pk_fma(splat2(ax[e]), we0, gg);
                gg = pk_fma(splat2(ay[e]), we1, gg);
                gg = pk_fma(splat2(ad[e]), we2, gg);
                f32x2 lk = pk_max(gg, gg * splat2(NEG_SLOPE));
                lpacc[e] = pk_fma(lk, vat, lpacc[e]);
            }
        }
    }
    float lp[9];
#pragma unroll
    for (int e = 0; e < 9; ++e) lp[e] = lpacc[e].x + lpacc[e].y;

    // ---- exchange partials with sibling channel-half ----
#define LPX(gg, cc2, ss, ee) lds_lp[(((gg) * 2 + (cc2)) * 64 + (ss)) * 9 + (ee)]
#pragma unroll
    for (int e = 0; e < 9; ++e) LPX(g, ch, lane, e) = lp[e];
    __syncthreads();    // B1

    float lg[9];
#pragma unroll
    for (int e = 0; e < 9; ++e) lg[e] = lp[e] + LPX(g, 1 - ch, lane, e);

    // ---- softmax per target (logits O(10), no max-sub) + pooled relu-sum ----
    f32x2 vb[4];
#pragma unroll
    for (int cc = 0; cc < 4; ++cc) vb[cc] = ld2(bias + CB + cc * 2);
    f32x2 hs[4] = {{0,0},{0,0},{0,0},{0,0}};
    const f32x2 zero2 = {0.f, 0.f};
#pragma unroll
    for (int i = 0; i < 3; ++i) {
        float e0 = __expf(lg[i]);
        float e1 = __expf(lg[3 + i]);
        float e2 = __expf(lg[6 + i]);
        float inv = __builtin_amdgcn_rcpf(e0 + e1 + e2);
        f32x2 a0 = splat2(e0 * inv), a1 = splat2(e1 * inv), a2 = splat2(e2 * inv);
#pragma unroll
        for (int cc = 0; cc < 4; ++cc) {
            f32x2 v = pk_fma(a0, xl[0][cc],
                      pk_fma(a1, xl[1][cc],
                      pk_fma(a2, xl[2][cc], vb[cc])));
            hs[cc] += pk_max(v, zero2);
        }
    }

    // ---- publish pooled h as bf16 into LDS ----
    {
        bf16x8 hv;
#pragma unroll
        for (int cc = 0; cc < 4; ++cc) {
            hv[cc * 2 + 0] = (__bf16)hs[cc].x;
            hv[cc * 2 + 1] = (__bf16)hs[cc].y;
        }
        *reinterpret_cast<bf16x8*>(&lds_h[lane][g * 16 + CB]) = hv;
    }
    __syncthreads();    // B2: h ready

    // ---------- phase 2: MLP via MFMA 16x16x32 bf16 (R8 layout, frags in VGPRs) ----------
    const int l15 = lane & 15;
    const int l4  = lane >> 4;
    const f32x4 zero4 = {0.f, 0.f, 0.f, 0.f};

    float b1v[8], b2v[2];
#pragma unroll
    for (int n = 0; n < 8; ++n) b1v[n] = b1[n * 16 + l15];
#pragma unroll
    for (int nn = 0; nn < 2; ++nn) b2v[nn] = b2[nn * 16 + l15];

    // layer 1: z[16x128] = h[16x32] @ W1 + b1, relu
    bf16x8 a1 = *reinterpret_cast<const bf16x8*>(&lds_h[wu * 16 + l15][l4 * 8]);
    f32x4 acc[8];
#pragma unroll
    for (int n = 0; n < 8; ++n)
        acc[n] = __builtin_amdgcn_mfma_f32_16x16x32_bf16(a1, w1f[n], zero4, 0, 0, 0);
#pragma unroll
    for (int r = 0; r < 4; ++r) {
        bf16x8 zv;
#pragma unroll
        for (int n = 0; n < 8; ++n) zv[n] = (__bf16)relu_f(acc[n][r] + b1v[n]);
        *reinterpret_cast<bf16x8*>(&lds_z[wu][l4 * 4 + r][l15 * 8]) = zv;
    }

    // layer 2: o[16x32] = z @ W2 + b2 (same-wave z reuse, compiler waits lgkmcnt)
    f32x4 o2[2] = {zero4, zero4};
#pragma unroll
    for (int ks = 0; ks < 4; ++ks) {
        bf16x8 a2 = *reinterpret_cast<const bf16x8*>(&lds_z[wu][l15][ks * 32 + l4 * 8]);
#pragma unroll
        for (int nn = 0; nn < 2; ++nn)
            o2[nn] = __builtin_amdgcn_mfma_f32_16x16x32_bf16(a2, w2f[ks * 2 + nn], o2[nn], 0, 0, 0);
    }

    // store: lane holds o[l4*4+r][nn*16+l15]
#pragma unroll
    for (int nn = 0; nn < 2; ++nn) {
#pragma unroll
        for (int r = 0; r < 4; ++r) {
            int row = blockIdx.x * 64 + wu * 16 + l4 * 4 + r;
            if (row < Btot)
                out[(size_t)row * 32 + nn * 16 + l15] = o2[nn][r] + b2v[nn];
        }
    }
}

extern "C" void kernel_launch(void* const* d_in, const int* in_sizes, int n_in,
                              void* d_out, int out_size, void* d_ws, size_t ws_size,
                              hipStream_t stream) {
    const float* agent_pos = (const float*)d_in[0];
    const float* agent_vel = (const float*)d_in[1];
    const float* rel_lm    = (const float*)d_in[2];
    const float* other_pos = (const float*)d_in[3];
    const float* lm_pos    = (const float*)d_in[4];
    const float* Wl   = (const float*)d_in[5];
    const float* bl   = (const float*)d_in[6];
    const float* Wr   = (const float*)d_in[7];
    const float* br   = (const float*)d_in[8];
    const float* We   = (const float*)d_in[9];
    const float* att  = (const float*)d_in[10];
    const float* bias = (const float*)d_in[11];
    const float* W1   = (const float*)d_in[12];
    const float* b1   = (const float*)d_in[13];
    const float* W2   = (const float*)d_in[14];
    const float* b2   = (const float*)d_in[15];
    float* out = (float*)d_out;

    __bf16* W1F = (__bf16*)d_ws;                   // 8 KB
    __bf16* W2F = (__bf16*)((char*)d_ws + 8192);   // 8 KB

    prep_weights<<<32, 256, 0, stream>>>(W1, W2, W1F, W2F);

    int B = in_sizes[0] / 6;                  // agent_pos is [B,3,2]
    int grid = (B + 63) / 64;
    scl_fused_kernel<<<grid, 256, 0, stream>>>(
        agent_pos, agent_vel, rel_lm, other_pos, lm_pos,
        Wl, bl, Wr, br, We, att, bias,
        (const bf16x8*)W1F, b1, (const bf16x8*)W2F, b2, out, B);
}